// Round 1
// baseline (332.782 us; speedup 1.0000x reference)
//
#include <hip/hip_runtime.h>
#include <hip/hip_bf16.h>

typedef unsigned short u16;
typedef short short8_t __attribute__((ext_vector_type(8)));
typedef float floatx4 __attribute__((ext_vector_type(4)));

// ---- sizes ----
constexpr int NT = 4096;     // tokens
constexpr int H  = 128;      // hidden
constexpr int NL = 4;        // layers
constexpr int CAP = 64;      // neighbor cap (Poisson(15.6) tail @64 ~ 1e-20)

// bf16 weight arena element offsets
constexpr int OFF_QKV  = 0;                       // 4*384*128
constexpr int OFF_AO   = OFF_QKV + 196608;
constexpr int OFF_F1   = OFF_AO  + 65536;
constexpr int OFF_F2   = OFF_F1  + 131072;
constexpr int OFF_LAT1 = OFF_F2  + 131072;
constexpr int OFF_B1   = OFF_LAT1 + 16384;        // contiguous after lat1 -> N=192 fused head GEMM
constexpr int OFF_LAT2 = OFF_B1  + 8192;
constexpr int W_TOTAL  = OFF_LAT2 + 2048;         // 550912 elements

__device__ __forceinline__ float bfu(u16 u) { return __uint_as_float(((unsigned)u) << 16); }
__device__ __forceinline__ u16 f2bf(float f) {
  unsigned u = __float_as_uint(f);
  u += 0x7fffu + ((u >> 16) & 1u);          // RNE
  return (u16)(u >> 16);
}
__device__ __forceinline__ void unpack8(uint4 u, float* f) {
  f[0] = __uint_as_float(u.x << 16); f[1] = __uint_as_float(u.x & 0xffff0000u);
  f[2] = __uint_as_float(u.y << 16); f[3] = __uint_as_float(u.y & 0xffff0000u);
  f[4] = __uint_as_float(u.z << 16); f[5] = __uint_as_float(u.z & 0xffff0000u);
  f[6] = __uint_as_float(u.w << 16); f[7] = __uint_as_float(u.w & 0xffff0000u);
}

// ---- weight f32 -> bf16 arena ----
__global__ void wconv_kernel(const float* __restrict__ qkv, const float* __restrict__ ao,
                             const float* __restrict__ f1,  const float* __restrict__ f2,
                             const float* __restrict__ lat1,const float* __restrict__ b1,
                             const float* __restrict__ lat2, u16* __restrict__ W) {
  for (int i = blockIdx.x * blockDim.x + threadIdx.x; i < W_TOTAL; i += gridDim.x * blockDim.x) {
    float v;
    if      (i < OFF_AO)   v = qkv[i - OFF_QKV];
    else if (i < OFF_F1)   v = ao[i - OFF_AO];
    else if (i < OFF_F2)   v = f1[i - OFF_F1];
    else if (i < OFF_LAT1) v = f2[i - OFF_F2];
    else if (i < OFF_B1)   v = lat1[i - OFF_LAT1];
    else if (i < OFF_LAT2) v = b1[i - OFF_B1];
    else                   v = lat2[i - OFF_LAT2];
    W[i] = f2bf(v);
  }
}

// ---- neighbor list (dR <= 0.2), mask is layer/head invariant & symmetric ----
__global__ __launch_bounds__(256) void build_nbrs_kernel(const float* __restrict__ xr,
                                                         int* __restrict__ nidx,
                                                         int* __restrict__ ncnt) {
  const int q = blockIdx.x, t = threadIdx.x;
  __shared__ unsigned long long words[64];
  const double eq = (double)xr[q * 16 + 1] * 5.24 - 2.62;
  const double pq = (double)xr[q * 16 + 2] * 6.2832 - 3.1416;
  const double TWO_PI = 6.283185307179586, INV_TWO_PI = 0.15915494309189535;
  for (int c = 0; c < 16; ++c) {
    const int k = c * 256 + t;
    const double ek = (double)xr[k * 16 + 1] * 5.24 - 2.62;
    const double pk = (double)xr[k * 16 + 2] * 6.2832 - 3.1416;
    const double de = eq - ek;
    double dp = pq - pk;
    dp -= TWO_PI * rint(dp * INV_TWO_PI);   // == arctan2(sin,cos) wrap
    const bool hit = (de * de + dp * dp) <= 0.04;
    unsigned long long m = __ballot(hit);   // 64 consecutive k per wave
    if ((t & 63) == 0) words[c * 4 + (t >> 6)] = m;
  }
  __syncthreads();
  if (t < 64) {
    unsigned long long m = words[t];
    const int cnt = __popcll(m);
    int incl = cnt;
    for (int off = 1; off < 64; off <<= 1) {
      int n = __shfl_up(incl, off);
      if (t >= off) incl += n;
    }
    int pos = incl - cnt;
    while (m) {
      const int b = __builtin_ctzll(m);
      m &= m - 1;
      if (pos < CAP) nidx[q * CAP + pos] = t * 64 + b;
      ++pos;
    }
    if (t == 63) ncnt[q] = incl > CAP ? CAP : incl;
  }
}

// ---- input projection: x = x_raw @ in_w.T + in_b  (K=16) ----
__global__ __launch_bounds__(128) void in_proj_kernel(const float* __restrict__ xr,
                                                      const float* __restrict__ w,
                                                      const float* __restrict__ b,
                                                      float* __restrict__ x) {
  __shared__ float s[16][16];
  const int j = threadIdx.x, r0 = blockIdx.x * 16;
  for (int idx = j; idx < 256; idx += 128) s[idx >> 4][idx & 15] = xr[r0 * 16 + idx];
  float wj[16];
#pragma unroll
  for (int k = 0; k < 16; ++k) wj[k] = w[j * 16 + k];
  const float bj = b[j];
  __syncthreads();
#pragma unroll
  for (int r = 0; r < 16; ++r) {
    float acc = bj;
#pragma unroll
    for (int k = 0; k < 16; ++k) acc += s[r][k] * wj[k];
    x[(r0 + r) * H + j] = acc;
  }
}

// ---- GEMM, fp32 A (optional fused LayerNorm), bf16 B [N x 128], bf16 out ----
// block: 64x64 tile; 4 waves as 2x2 of 32x32; mfma 16x16x32 bf16
template <bool DO_LN, bool RELU>
__global__ __launch_bounds__(256) void gemm_f32a_kernel(
    const float* __restrict__ A, const float* __restrict__ lns, const float* __restrict__ lnb,
    const u16* __restrict__ B, const float* __restrict__ bias1,
    const float* __restrict__ bias2, int bsplit,
    u16* __restrict__ C, int Ncols, int ldc) {
  __shared__ __align__(16) u16 As[64][136];   // +8 pad: 2-way LDS aliasing only (free)
  const int m0 = blockIdx.x * 64, n0 = blockIdx.y * 64, t = threadIdx.x;
  {
    const int r = t >> 2, s4 = t & 3;
    const float* xp = A + (size_t)(m0 + r) * H + s4 * 32;
    float v[32];
#pragma unroll
    for (int i = 0; i < 32; i += 4) {
      float4 f = *(const float4*)(xp + i);
      v[i] = f.x; v[i + 1] = f.y; v[i + 2] = f.z; v[i + 3] = f.w;
    }
    if (DO_LN) {
      float sum = 0.f, ss = 0.f;
#pragma unroll
      for (int i = 0; i < 32; ++i) { sum += v[i]; ss += v[i] * v[i]; }
      sum += __shfl_xor(sum, 1); sum += __shfl_xor(sum, 2);
      ss  += __shfl_xor(ss, 1);  ss  += __shfl_xor(ss, 2);
      const float mean = sum * (1.f / 128.f);
      const float var  = ss * (1.f / 128.f) - mean * mean;
      const float rstd = rsqrtf(var + 1e-5f);
#pragma unroll
      for (int i = 0; i < 32; ++i) {
        const int col = s4 * 32 + i;
        v[i] = (v[i] - mean) * rstd * lns[col] + lnb[col];
      }
    }
#pragma unroll
    for (int i = 0; i < 32; ++i) As[r][s4 * 32 + i] = f2bf(v[i]);
  }
  __syncthreads();
  const int lane = t & 63, w = t >> 6;
  const int wm = w >> 1, wn = w & 1, lr = lane & 15, quad = lane >> 4;
  const floatx4 FZ = {0.f, 0.f, 0.f, 0.f};
  const short8_t SZ = {0, 0, 0, 0, 0, 0, 0, 0};
  floatx4 acc[2][2];
  acc[0][0] = FZ; acc[0][1] = FZ; acc[1][0] = FZ; acc[1][1] = FZ;
#pragma unroll
  for (int k0 = 0; k0 < 128; k0 += 32) {
    short8_t afrag[2], bfrag[2];
#pragma unroll
    for (int mi = 0; mi < 2; ++mi)
      afrag[mi] = *(const short8_t*)&As[wm * 32 + mi * 16 + lr][k0 + quad * 8];
#pragma unroll
    for (int ni = 0; ni < 2; ++ni) {
      const int col = n0 + wn * 32 + ni * 16 + lr;
      bfrag[ni] = (col < Ncols) ? *(const short8_t*)&B[(size_t)col * 128 + k0 + quad * 8] : SZ;
    }
#pragma unroll
    for (int mi = 0; mi < 2; ++mi)
#pragma unroll
      for (int ni = 0; ni < 2; ++ni)
        acc[mi][ni] = __builtin_amdgcn_mfma_f32_16x16x32_bf16(afrag[mi], bfrag[ni], acc[mi][ni], 0, 0, 0);
  }
#pragma unroll
  for (int mi = 0; mi < 2; ++mi)
#pragma unroll
    for (int ni = 0; ni < 2; ++ni) {
      const int col = n0 + wn * 32 + ni * 16 + lr;
      if (col >= Ncols) continue;
      const float bv = (bias2 != nullptr && col >= bsplit) ? bias2[col - bsplit] : bias1[col];
#pragma unroll
      for (int r = 0; r < 4; ++r) {
        const int row = m0 + wm * 32 + mi * 16 + quad * 4 + r;
        float vv = acc[mi][ni][r] + bv;
        if (RELU) vv = fmaxf(vv, 0.f);
        C[(size_t)row * ldc + col] = f2bf(vv);
      }
    }
}

// ---- GEMM, bf16 A [M x K], bf16 B [128 x K], epilogue: x += out + bias ----
template <int K>
__global__ __launch_bounds__(256) void gemm_resid_kernel(
    const u16* __restrict__ A, const u16* __restrict__ B,
    const float* __restrict__ bias, float* __restrict__ X) {
  const int m0 = blockIdx.x * 64, n0 = blockIdx.y * 64, t = threadIdx.x;
  const int lane = t & 63, w = t >> 6;
  const int wm = w >> 1, wn = w & 1, lr = lane & 15, quad = lane >> 4;
  const floatx4 FZ = {0.f, 0.f, 0.f, 0.f};
  floatx4 acc[2][2];
  acc[0][0] = FZ; acc[0][1] = FZ; acc[1][0] = FZ; acc[1][1] = FZ;
#pragma unroll
  for (int k0 = 0; k0 < K; k0 += 32) {
    short8_t afrag[2], bfrag[2];
#pragma unroll
    for (int mi = 0; mi < 2; ++mi)
      afrag[mi] = *(const short8_t*)&A[(size_t)(m0 + wm * 32 + mi * 16 + lr) * K + k0 + quad * 8];
#pragma unroll
    for (int ni = 0; ni < 2; ++ni)
      bfrag[ni] = *(const short8_t*)&B[(size_t)(n0 + wn * 32 + ni * 16 + lr) * K + k0 + quad * 8];
#pragma unroll
    for (int mi = 0; mi < 2; ++mi)
#pragma unroll
      for (int ni = 0; ni < 2; ++ni)
        acc[mi][ni] = __builtin_amdgcn_mfma_f32_16x16x32_bf16(afrag[mi], bfrag[ni], acc[mi][ni], 0, 0, 0);
  }
#pragma unroll
  for (int mi = 0; mi < 2; ++mi)
#pragma unroll
    for (int ni = 0; ni < 2; ++ni) {
      const int col = n0 + wn * 32 + ni * 16 + lr;
      const float bv = bias[col];
#pragma unroll
      for (int r = 0; r < 4; ++r) {
        const int row = m0 + wm * 32 + mi * 16 + quad * 4 + r;
        X[(size_t)row * H + col] += acc[mi][ni][r] + bv;
      }
    }
}

// ---- sparse gather attention: one thread per (q, head) ----
__global__ __launch_bounds__(256) void attn_kernel(const u16* __restrict__ qkv,
                                                   const int* __restrict__ nidx,
                                                   const int* __restrict__ ncnt,
                                                   u16* __restrict__ obf) {
  const int tid = blockIdx.x * 256 + threadIdx.x;
  const int q = tid >> 3, h = tid & 7;
  const u16* qp = qkv + (size_t)q * 384 + h * 16;
  float qv[16];
  { uint4 a = *(const uint4*)qp; uint4 b = *(const uint4*)(qp + 8);
    unpack8(a, qv); unpack8(b, qv + 8); }
#pragma unroll
  for (int d = 0; d < 16; ++d) qv[d] *= 0.25f;   // 1/sqrt(HD), folded into q
  float o[16];
#pragma unroll
  for (int d = 0; d < 16; ++d) o[d] = 0.f;
  float se = 0.f;
  const int cnt = ncnt[q];
  const int* nl = nidx + q * CAP;
  for (int i = 0; i < cnt; ++i) {
    const int nb = nl[i];
    const u16* kp = qkv + (size_t)nb * 384 + 128 + h * 16;
    float kv[16], vv[16];
    { uint4 a = *(const uint4*)kp;         uint4 b = *(const uint4*)(kp + 8);
      unpack8(a, kv); unpack8(b, kv + 8); }
    { uint4 a = *(const uint4*)(kp + 128); uint4 b = *(const uint4*)(kp + 136);
      unpack8(a, vv); unpack8(b, vv + 8); }
    float s0 = 0.f, s1 = 0.f, s2 = 0.f, s3 = 0.f;
#pragma unroll
    for (int d = 0; d < 16; d += 4) {
      s0 += qv[d] * kv[d]; s1 += qv[d + 1] * kv[d + 1];
      s2 += qv[d + 2] * kv[d + 2]; s3 += qv[d + 3] * kv[d + 3];
    }
    const float e = expf((s0 + s1) + (s2 + s3));  // no max-sub: |s| < ~0.5, safe
    se += e;
#pragma unroll
    for (int d = 0; d < 16; ++d) o[d] += e * vv[d];
  }
  const float inv = 1.f / se;                     // cnt >= 1 (diagonal always in)
  u16* op = obf + (size_t)q * H + h * 16;
  uint4 r0, r1;
  r0.x = (unsigned)f2bf(o[0] * inv)  | ((unsigned)f2bf(o[1] * inv) << 16);
  r0.y = (unsigned)f2bf(o[2] * inv)  | ((unsigned)f2bf(o[3] * inv) << 16);
  r0.z = (unsigned)f2bf(o[4] * inv)  | ((unsigned)f2bf(o[5] * inv) << 16);
  r0.w = (unsigned)f2bf(o[6] * inv)  | ((unsigned)f2bf(o[7] * inv) << 16);
  r1.x = (unsigned)f2bf(o[8] * inv)  | ((unsigned)f2bf(o[9] * inv) << 16);
  r1.y = (unsigned)f2bf(o[10] * inv) | ((unsigned)f2bf(o[11] * inv) << 16);
  r1.z = (unsigned)f2bf(o[12] * inv) | ((unsigned)f2bf(o[13] * inv) << 16);
  r1.w = (unsigned)f2bf(o[14] * inv) | ((unsigned)f2bf(o[15] * inv) << 16);
  *(uint4*)op = r0; *(uint4*)(op + 8) = r1;
}

// ---- heads: lat = normalize(t1 @ lat2.T + b), beta = clip(sigmoid(t2 @ b2.T + b)) ----
// g: [4096][192] bf16, cols 0..127 = relu(x@lat1.T+b), 128..191 = relu(x@b1.T+b)
__global__ __launch_bounds__(256) void heads2_kernel(const u16* __restrict__ g,
                                                     const u16* __restrict__ lat2w,
                                                     const float* __restrict__ lat2b,
                                                     const float* __restrict__ b2w,
                                                     const float* __restrict__ b2b,
                                                     float* __restrict__ out) {
  const int row = blockIdx.x * 4 + (threadIdx.x >> 6);
  const int lane = threadIdx.x & 63;
  const u16* t1 = g + (size_t)row * 192;
  const int c = lane & 15, ch = lane >> 4;
  float acc = 0.f;
  const u16* ap = t1 + ch * 32;
  const u16* bp = lat2w + c * 128 + ch * 32;
  for (int j = 0; j < 32; ++j) acc += bfu(ap[j]) * bfu(bp[j]);
  acc += __shfl_xor(acc, 16);
  acc += __shfl_xor(acc, 32);
  acc += lat2b[c];
  float ss = acc * acc;
  ss += __shfl_xor(ss, 1); ss += __shfl_xor(ss, 2);
  ss += __shfl_xor(ss, 4); ss += __shfl_xor(ss, 8);
  const float nrm = fmaxf(sqrtf(ss), 1e-12f);
  if (lane < 16) out[NT + row * 16 + c] = acc / nrm;
  // beta
  float v = bfu(t1[128 + lane]) * b2w[lane];
  v += __shfl_xor(v, 1); v += __shfl_xor(v, 2); v += __shfl_xor(v, 4);
  v += __shfl_xor(v, 8); v += __shfl_xor(v, 16); v += __shfl_xor(v, 32);
  v += b2b[0];
  float beta = 1.f / (1.f + expf(-v));
  beta = fminf(fmaxf(beta, 1e-6f), 1.f - 1e-6f);
  if (lane == 0) out[row] = beta;
}

extern "C" void kernel_launch(void* const* d_in, const int* in_sizes, int n_in,
                              void* d_out, int out_size, void* d_ws, size_t ws_size,
                              hipStream_t stream) {
  const float* x_raw  = (const float*)d_in[0];
  const float* in_w   = (const float*)d_in[2];
  const float* in_b   = (const float*)d_in[3];
  const float* ln1_s  = (const float*)d_in[4];
  const float* ln1_b  = (const float*)d_in[5];
  const float* qkv_w  = (const float*)d_in[6];
  const float* qkv_b  = (const float*)d_in[7];
  const float* ao_w   = (const float*)d_in[8];
  const float* ao_b   = (const float*)d_in[9];
  const float* ln2_s  = (const float*)d_in[10];
  const float* ln2_b  = (const float*)d_in[11];
  const float* f1_w   = (const float*)d_in[12];
  const float* f1_b   = (const float*)d_in[13];
  const float* f2_w   = (const float*)d_in[14];
  const float* f2_b   = (const float*)d_in[15];
  const float* lat1_w = (const float*)d_in[16];
  const float* lat1_b = (const float*)d_in[17];
  const float* lat2_w = (const float*)d_in[18];
  const float* lat2_b = (const float*)d_in[19];
  const float* b1_w   = (const float*)d_in[20];
  const float* b1_b   = (const float*)d_in[21];
  const float* b2_w   = (const float*)d_in[22];
  const float* b2_b   = (const float*)d_in[23];
  float* out = (float*)d_out;

  char* p = (char*)d_ws;
  u16* W    = (u16*)p;  p += ((size_t)W_TOTAL * 2 + 255) & ~(size_t)255;
  float* X  = (float*)p; p += (size_t)NT * H * 4;
  u16* QKV  = (u16*)p;  p += (size_t)NT * 384 * 2;
  u16* O    = (u16*)p;  p += (size_t)NT * H * 2;
  u16* FF1  = (u16*)p;  p += (size_t)NT * 256 * 2;
  u16* G57  = (u16*)p;  p += (size_t)NT * 192 * 2;
  int* NC   = (int*)p;  p += (size_t)NT * 4;
  int* NI   = (int*)p;  p += (size_t)NT * CAP * 4;

  wconv_kernel<<<512, 256, 0, stream>>>(qkv_w, ao_w, f1_w, f2_w, lat1_w, b1_w, lat2_w, W);
  build_nbrs_kernel<<<NT, 256, 0, stream>>>(x_raw, NI, NC);
  in_proj_kernel<<<NT / 16, 128, 0, stream>>>(x_raw, in_w, in_b, X);

  for (int l = 0; l < NL; ++l) {
    gemm_f32a_kernel<true, false><<<dim3(64, 6), 256, 0, stream>>>(
        X, ln1_s + l * 128, ln1_b + l * 128, W + OFF_QKV + l * 49152,
        qkv_b + l * 384, nullptr, 1 << 30, QKV, 384, 384);
    attn_kernel<<<NT * 8 / 256, 256, 0, stream>>>(QKV, NI, NC, O);
    gemm_resid_kernel<128><<<dim3(64, 2), 256, 0, stream>>>(
        O, W + OFF_AO + l * 16384, ao_b + l * 128, X);
    gemm_f32a_kernel<true, true><<<dim3(64, 4), 256, 0, stream>>>(
        X, ln2_s + l * 128, ln2_b + l * 128, W + OFF_F1 + l * 32768,
        f1_b + l * 256, nullptr, 1 << 30, FF1, 256, 256);
    gemm_resid_kernel<256><<<dim3(64, 2), 256, 0, stream>>>(
        FF1, W + OFF_F2 + l * 32768, f2_b + l * 128, X);
  }

  gemm_f32a_kernel<false, true><<<dim3(64, 3), 256, 0, stream>>>(
      X, nullptr, nullptr, W + OFF_LAT1, lat1_b, b1_b, 128, G57, 192, 192);
  heads2_kernel<<<NT / 4, 256, 0, stream>>>(G57, W + OFF_LAT2, lat2_b, b2_w, b2_b, out);
}